// Round 10
// baseline (2492.896 us; speedup 1.0000x reference)
//
#include <hip/hip_runtime.h>

#define D 48
#define C 16
#define H 128
#define D3 (D*D*D)
#define NVOX (2*D3)           // 221184
#define NB_FC (NVOX/256)      // 864
#define BN_EPS 1e-5f

// padded channel-major volume: [b][c][54 z][54 y][56 x]
#define PROW 56
#define PPL  (54*PROW)        // 3024
#define PVOL (54*PPL)         // 163296
#define NPAD (54*54*54)       // 157464

typedef unsigned short u16;
typedef unsigned int   u32;

__device__ __forceinline__ float bf2f(u16 u) {
    union { u32 i; float f; } p; p.i = ((u32)u) << 16; return p.f;
}
__device__ __forceinline__ u16 f2bf(float f) {
    union { float f; u32 i; } p; p.f = f;
    u32 r = p.i + 0x7fffu + ((p.i >> 16) & 1u);   // RTNE
    return (u16)(r >> 16);
}
__device__ __forceinline__ int refl(int i) {
    return i < 0 ? -i : (i >= D ? 2*D - 2 - i : i);
}
__device__ __forceinline__ void fma4(float4& a, float s, const float4 w) {
    a.x = fmaf(s, w.x, a.x); a.y = fmaf(s, w.y, a.y);
    a.z = fmaf(s, w.z, a.z); a.w = fmaf(s, w.w, a.w);
}

// ---------------------------------------------------------------------------
// k_pad0: build full padded volume from channels-last x_in (once, step 0).
// ---------------------------------------------------------------------------
__global__ __launch_bounds__(256)
void k_pad0(const float* __restrict__ x, float* __restrict__ xp) {
    const int idx = blockIdx.x * 256 + threadIdx.x;     // 32*NPAD exactly
    const int bc = idx / NPAD;
    int r = idx - bc * NPAD;
    const int pz = r / 2916; r -= pz * 2916;
    const int py = r / 54;
    const int px = r - py * 54;
    const int b = bc >> 4, c = bc & 15;
    const int z = refl(pz - 3), y = refl(py - 3), x0 = refl(px - 3);
    xp[(size_t)bc*PVOL + pz*PPL + py*PROW + px] =
        x[(((size_t)(b*D + z))*D + y)*D*C + x0*C + c];
}

// ---------------------------------------------------------------------------
// k_wxpose: conv weights -> wt[c][dy][dz][dx]; w1[j][c] -> w1t[c][j]. Once.
// ---------------------------------------------------------------------------
__global__ __launch_bounds__(256)
void k_wxpose(const float* __restrict__ cw, float* __restrict__ wt,
              const float* __restrict__ w1, float* __restrict__ w1t) {
    int i = blockIdx.x * 256 + threadIdx.x;
    if (i < 343 * 16) {
        int kidx = i >> 4, c = i & 15;           // kidx = (dz*7+dy)*7+dx
        int dz = kidx / 49, dy = (kidx / 7) % 7, dx = kidx % 7;
        wt[((c*7 + dy)*7 + dz)*7 + dx] = cw[i];
    }
    if (i < H * C) {
        int j = i >> 4, c = i & 15;
        w1t[c * H + j] = w1[i];
    }
}

// ---------------------------------------------------------------------------
// k_conv v6: no LDS, no barriers; weights REGISTER-CACHED per dy (49 floats,
// compile-time indexed: dy runtime loop, pz(9) x k(3) unrolled, dz = pz-k).
// Weight VMEM 1029 -> 91 loads/thread. Inputs: 189 aligned float4 reads via
// L1/L2. Writes y1 channel-major ushort4.
// ---------------------------------------------------------------------------
__global__ __launch_bounds__(192)
void k_conv(const float* __restrict__ xp, const float* __restrict__ wt,
            const float* __restrict__ cbias, u16* __restrict__ y1m) {
    const int bid = blockIdx.x;
    const int zt = bid & 15;          // 16 z-tiles of 3
    const int yt = (bid >> 4) % 3;    // 3 y-tiles of 16
    const int c  = (bid / 48) & 15;
    const int b  = bid / 768;
    const int t  = threadIdx.x;
    const int tx = t % 12, ty = t / 12;
    const int y0 = yt * 16, z0 = zt * 3;
    const float* base = xp + (size_t)(b*16 + c) * PVOL
                           + (size_t)(y0 + ty) * PROW + 4*tx
                           + (size_t)z0 * PPL;
    const float* wc = wt + c * 343;   // [dy][dz][dx]

    float a[3][4];
    #pragma unroll
    for (int k = 0; k < 3; ++k)
        a[k][0] = a[k][1] = a[k][2] = a[k][3] = 0.f;

    for (int dy = 0; dy < 7; ++dy) {              // runtime: body fits I$
        // register-cache the 49 weights of this dy (compile-time indexed)
        float w[49];
        const float* wrow = wc + dy*49;
        #pragma unroll
        for (int q = 0; q < 12; ++q) {
            float4 p = *(const float4*)(wrow + q*4);
            w[q*4+0] = p.x; w[q*4+1] = p.y; w[q*4+2] = p.z; w[q*4+3] = p.w;
        }
        w[48] = wrow[48];
        const float* rowb = base + (size_t)dy * PROW;
        #pragma unroll
        for (int pz = 0; pz < 9; ++pz) {          // input plane zi = z0+pz-3
            const float* rp = rowb + (size_t)pz * PPL;
            float4 A  = *(const float4*)rp;
            float4 Bv = *(const float4*)(rp + 4);
            float4 Cv = *(const float4*)(rp + 8);
            #pragma unroll
            for (int k = 0; k < 3; ++k) {
                const int dz = pz - k;            // compile-time
                if (dz >= 0 && dz <= 6) {
                    const float w0=w[dz*7+0], w1=w[dz*7+1], w2=w[dz*7+2],
                                w3=w[dz*7+3], w4=w[dz*7+4], w5=w[dz*7+5],
                                w6=w[dz*7+6];
                    a[k][0] = fmaf(w0,A.x, fmaf(w1,A.y, fmaf(w2,A.z, fmaf(w3,A.w,
                              fmaf(w4,Bv.x, fmaf(w5,Bv.y, fmaf(w6,Bv.z, a[k][0])))))));
                    a[k][1] = fmaf(w0,A.y, fmaf(w1,A.z, fmaf(w2,A.w, fmaf(w3,Bv.x,
                              fmaf(w4,Bv.y, fmaf(w5,Bv.z, fmaf(w6,Bv.w, a[k][1])))))));
                    a[k][2] = fmaf(w0,A.z, fmaf(w1,A.w, fmaf(w2,Bv.x, fmaf(w3,Bv.y,
                              fmaf(w4,Bv.z, fmaf(w5,Bv.w, fmaf(w6,Cv.x, a[k][2])))))));
                    a[k][3] = fmaf(w0,A.w, fmaf(w1,Bv.x, fmaf(w2,Bv.y, fmaf(w3,Bv.z,
                              fmaf(w4,Bv.w, fmaf(w5,Cv.x, fmaf(w6,Cv.y, a[k][3])))))));
                }
            }
        }
    }

    const float cbv = cbias[c];
    const size_t cb_off = (size_t)(b*16 + c) * D3;
    #pragma unroll
    for (int k = 0; k < 3; ++k) {
        const size_t sp = (size_t)(z0+k)*2304 + (y0+ty)*48 + 4*tx;
        ushort4 o = { f2bf(a[k][0]+cbv), f2bf(a[k][1]+cbv),
                      f2bf(a[k][2]+cbv), f2bf(a[k][3]+cbv) };
        *(ushort4*)(y1m + cb_off + sp) = o;
    }
}

// ---------------------------------------------------------------------------
// k_fc0: h = [x|y1]@W0 + b0 -> bf16 h + deterministic BN partials.
// y1 (channel-major) staged via LDS: 4 coalesced ushort4 loads/thread ->
// ys[c][vox]; compute reads are same-address broadcasts (free).
// ---------------------------------------------------------------------------
__global__ __launch_bounds__(256)
void k_fc0(const float* __restrict__ srcx, const u16* __restrict__ y1m,
           const float* __restrict__ w0, const float* __restrict__ b0,
           u16* __restrict__ hb, float* __restrict__ partials) {
    __shared__ u16 ys[16][260];       // 8320 B
    __shared__ float red[2][8][H];    // 8192 B
    const int t = threadIdx.x;
    const int vb0 = blockIdx.x * 256;
    const int b  = vb0 / D3;
    const int sp0 = vb0 - b * D3;
    {   // stage y1 tile: 16 c x 256 vox
        const u16* yb = y1m + (size_t)b*16*D3 + sp0;
        #pragma unroll
        for (int r = 0; r < 4; ++r) {
            const int idx = t + 256*r;
            const int cc = idx >> 6, q = idx & 63;
            *(ushort4*)&ys[cc][q*4] = *(const ushort4*)(yb + (size_t)cc*D3 + q*4);
        }
    }
    const int j4 = t & 31, vg = t >> 5;
    const int j0 = j4 * 4;
    float4 wr[32];
    #pragma unroll
    for (int k = 0; k < 32; ++k) wr[k] = *(const float4*)(w0 + k*H + j0);
    const float4 bv = *(const float4*)(b0 + j0);
    __syncthreads();

    float4 sum = {0.f,0.f,0.f,0.f}, sq = {0.f,0.f,0.f,0.f};
    const int vloc = vg * 32;
    const float* xc = srcx + (size_t)(vb0 + vloc) * C;
    for (int i = 0; i < 32; ++i) {
        const int vi = vloc + i;
        float4 h = bv;
        {   // x part: 4 broadcast float4 loads
            const float4* xp4 = (const float4*)(xc + i*C);
            float4 x0 = xp4[0], x1 = xp4[1], x2 = xp4[2], x3 = xp4[3];
            fma4(h, x0.x, wr[0]);  fma4(h, x0.y, wr[1]);
            fma4(h, x0.z, wr[2]);  fma4(h, x0.w, wr[3]);
            fma4(h, x1.x, wr[4]);  fma4(h, x1.y, wr[5]);
            fma4(h, x1.z, wr[6]);  fma4(h, x1.w, wr[7]);
            fma4(h, x2.x, wr[8]);  fma4(h, x2.y, wr[9]);
            fma4(h, x2.z, wr[10]); fma4(h, x2.w, wr[11]);
            fma4(h, x3.x, wr[12]); fma4(h, x3.y, wr[13]);
            fma4(h, x3.z, wr[14]); fma4(h, x3.w, wr[15]);
        }
        #pragma unroll
        for (int k = 0; k < 16; ++k)
            fma4(h, bf2f(ys[k][vi]), wr[16+k]);
        sum.x += h.x; sum.y += h.y; sum.z += h.z; sum.w += h.w;
        sq.x = fmaf(h.x,h.x,sq.x); sq.y = fmaf(h.y,h.y,sq.y);
        sq.z = fmaf(h.z,h.z,sq.z); sq.w = fmaf(h.w,h.w,sq.w);
        ushort4 hu = { f2bf(h.x), f2bf(h.y), f2bf(h.z), f2bf(h.w) };
        *(ushort4*)(hb + (size_t)(vb0 + vi)*H + j0) = hu;
    }
    *(float4*)&red[0][vg][j0] = sum;
    *(float4*)&red[1][vg][j0] = sq;
    __syncthreads();
    const int stat = t >> 7, j = t & 127;
    float acc = 0.f;
    #pragma unroll
    for (int g = 0; g < 8; ++g) acc += red[stat][g][j];
    partials[(size_t)t * NB_FC + blockIdx.x] = acc;
}

// ---------------------------------------------------------------------------
__global__ __launch_bounds__(256)
void k_red(const float* __restrict__ partials, float* __restrict__ sums) {
    const int s = blockIdx.x, t = threadIdx.x;
    const float* row = partials + (size_t)s * NB_FC;
    float a = row[t] + row[t + 256] + row[t + 512];
    if (t + 768 < NB_FC) a += row[t + 768];
    __shared__ float l[256];
    l[t] = a; __syncthreads();
    if (t < 128) l[t] += l[t + 128];
    __syncthreads();
    if (t < 64) {
        float v = l[t] + l[t + 64];
        #pragma unroll
        for (int off = 32; off; off >>= 1) v += __shfl_down(v, off);
        if (t == 0) sums[s] = v;
    }
}

// ---------------------------------------------------------------------------
// k_apply: 64 voxels/block. BN+ReLU -> LDS; fc1 vs global pre-transposed w1t
// (L1 broadcast); masked residual -> d_out (channels-last) AND padded volume
// (interior + reflected halo duplicates -> k_halo kernel eliminated).
// ---------------------------------------------------------------------------
__global__ __launch_bounds__(256)
void k_apply(const u16* __restrict__ hb, const float* __restrict__ srcx,
             const float* __restrict__ w1t,
             const float* __restrict__ gamma, const float* __restrict__ beta,
             const float* __restrict__ sums, const int* __restrict__ mask,
             float* __restrict__ xo, float* __restrict__ xp) {
    __shared__ float hs[64][132];     // 33792 B
    __shared__ float xs[16][68];      //  4352 B
    const int t = threadIdx.x;
    const size_t vb = (size_t)blockIdx.x * 64;

    {   // phase A: BN-affine + ReLU into LDS
        const int j4 = t & 31, vh = t >> 5;
        const int j0 = j4 * 4;
        const float invN = 1.0f / (float)NVOX;
        const float4 sm = *(const float4*)(sums + j0);
        const float4 sQ = *(const float4*)(sums + H + j0);
        const float4 gm = *(const float4*)(gamma + j0);
        const float4 bt = *(const float4*)(beta + j0);
        float4 sc, sh;
        {
            float m0 = sm.x*invN, m1 = sm.y*invN, m2 = sm.z*invN, m3 = sm.w*invN;
            sc.x = gm.x * rsqrtf(fmaf(-m0,m0,sQ.x*invN) + BN_EPS);
            sc.y = gm.y * rsqrtf(fmaf(-m1,m1,sQ.y*invN) + BN_EPS);
            sc.z = gm.z * rsqrtf(fmaf(-m2,m2,sQ.z*invN) + BN_EPS);
            sc.w = gm.w * rsqrtf(fmaf(-m3,m3,sQ.w*invN) + BN_EPS);
            sh.x = bt.x - m0*sc.x; sh.y = bt.y - m1*sc.y;
            sh.z = bt.z - m2*sc.z; sh.w = bt.w - m3*sc.w;
        }
        #pragma unroll
        for (int rep = 0; rep < 8; ++rep) {
            const int vl = rep*8 + vh;
            ushort4 u = *(const ushort4*)(hb + (vb + vl)*H + j0);
            float4 hp;
            hp.x = fmaxf(0.f, fmaf(bf2f(u.x), sc.x, sh.x));
            hp.y = fmaxf(0.f, fmaf(bf2f(u.y), sc.y, sh.y));
            hp.z = fmaxf(0.f, fmaf(bf2f(u.z), sc.z, sh.z));
            hp.w = fmaxf(0.f, fmaf(bf2f(u.w), sc.w, sh.w));
            *(float4*)&hs[vl][j0] = hp;
        }
    }
    __syncthreads();
    {   // phase B: dx = h'@W1 (w1t from global, L1 broadcast), residual
        const int c = t & 15, vi0 = t >> 4;
        const float* w1c = w1t + c * H;
        #pragma unroll
        for (int rep = 0; rep < 4; ++rep) {
            const int vi = rep*16 + vi0;
            const size_t v = vb + vi;
            float4 acc = {0.f,0.f,0.f,0.f};
            #pragma unroll
            for (int j = 0; j < H; j += 4) {
                float4 hv = *(const float4*)&hs[vi][j];
                float4 wv = *(const float4*)(w1c + j);
                acc.x = fmaf(hv.x, wv.x, acc.x); acc.y = fmaf(hv.y, wv.y, acc.y);
                acc.z = fmaf(hv.z, wv.z, acc.z); acc.w = fmaf(hv.w, wv.w, acc.w);
            }
            const float dx = (acc.x + acc.y) + (acc.z + acc.w);
            const float m = (float)mask[v];
            const float xold = srcx[v*C + c];
            const float xn = (c == 0) ? xold : fmaf(dx, m, xold);
            xo[v*C + c] = xn;
            xs[c][vi] = xn;
        }
    }
    __syncthreads();
    {   // phase C: padded-volume interior + reflected halo duplicates
        const int b = (int)(vb / D3);
        const int sp0 = (int)(vb % D3);
        #pragma unroll
        for (int r = 0; r < 4; ++r) {
            const int idx = t + 256*r;
            const int c2 = idx >> 6, vi = idx & 63;
            const int s = sp0 + vi;
            const int z = s / 2304, rem = s - z*2304;
            const int yy = rem / 48, x0 = rem - yy*48;
            const float xn = xs[c2][vi];
            float* vol = xp + (size_t)(b*16 + c2) * PVOL;
            int pz[2], py[2], px[2], nz=1, ny=1, nx=1;
            pz[0] = z+3; py[0] = yy+3; px[0] = x0+3;
            if (z  >= 1 && z  <= 3) pz[nz++] = 3 - z;
            else if (z  >= 44 && z  <= 46) pz[nz++] = 97 - z;
            if (yy >= 1 && yy <= 3) py[ny++] = 3 - yy;
            else if (yy >= 44 && yy <= 46) py[ny++] = 97 - yy;
            if (x0 >= 1 && x0 <= 3) px[nx++] = 3 - x0;
            else if (x0 >= 44 && x0 <= 46) px[nx++] = 97 - x0;
            for (int iz = 0; iz < nz; ++iz)
                for (int iy = 0; iy < ny; ++iy)
                    for (int ix = 0; ix < nx; ++ix)
                        vol[(size_t)pz[iz]*PPL + py[iy]*PROW + px[ix]] = xn;
        }
    }
}

// ---------------------------------------------------------------------------
extern "C" void kernel_launch(void* const* d_in, const int* in_sizes, int n_in,
                              void* d_out, int out_size, void* d_ws, size_t ws_size,
                              hipStream_t stream) {
    const float* x_in = (const float*)d_in[0];
    const float* cw   = (const float*)d_in[1];
    const float* cb   = (const float*)d_in[2];
    const float* w0   = (const float*)d_in[3];
    const float* b0   = (const float*)d_in[4];
    const float* w1   = (const float*)d_in[5];
    const float* gm   = (const float*)d_in[6];
    const float* bt   = (const float*)d_in[7];
    const int*   mk   = (const int*)d_in[8];
    float* out = (float*)d_out;

    char* p = (char*)d_ws;
    float* xp       = (float*)p;   p += (size_t)32 * PVOL * 4;      // 20.9MB
    u16*   y1m      = (u16*)p;     p += (size_t)NVOX * C * 2;       //  7.1MB
    u16*   hb       = (u16*)p;     p += (size_t)NVOX * H * 2;       // 56.6MB
    float* partials = (float*)p;   p += (size_t)256 * NB_FC * 4;    //  0.9MB
    float* sums     = (float*)p;   p += 256 * 4;
    float* wt       = (float*)p;   p += 343 * 16 * 4;
    float* w1t      = (float*)p;                                    // 2048

    k_pad0  <<<32*NPAD/256, 256, 0, stream>>>(x_in, xp);
    k_wxpose<<<22,          256, 0, stream>>>(cw, wt, w1, w1t);
    for (int s = 0; s < 8; ++s) {
        const float* srcx = (s == 0) ? x_in : out;
        k_conv <<<1536,    192, 0, stream>>>(xp, wt, cb, y1m);
        k_fc0  <<<NB_FC,   256, 0, stream>>>(srcx, y1m, w0, b0, hb, partials);
        k_red  <<<256,     256, 0, stream>>>(partials, sums);
        k_apply<<<NVOX/64, 256, 0, stream>>>(hb, srcx, w1t, gm, bt, sums,
                                             mk + (size_t)s * NVOX, out, xp);
    }
}

// Round 11
// 1313.136 us; speedup vs baseline: 1.8984x; 1.8984x over previous
//
#include <hip/hip_runtime.h>

#define D 48
#define C 16
#define H 128
#define D3 (D*D*D)
#define NVOX (2*D3)           // 221184
#define NB_FC (NVOX/256)      // 864
#define BN_EPS 1e-5f

// padded channel-major volume: [b][c][54 z][54 y][56 x]
#define PROW 56
#define PPL  (54*PROW)        // 3024
#define PVOL (54*PPL)         // 163296
#define NPAD (54*54*54)       // 157464

typedef unsigned short u16;
typedef unsigned int   u32;

__device__ __forceinline__ float bf2f(u16 u) {
    union { u32 i; float f; } p; p.i = ((u32)u) << 16; return p.f;
}
__device__ __forceinline__ u16 f2bf(float f) {
    union { float f; u32 i; } p; p.f = f;
    u32 r = p.i + 0x7fffu + ((p.i >> 16) & 1u);   // RTNE
    return (u16)(r >> 16);
}
__device__ __forceinline__ int refl(int i) {
    return i < 0 ? -i : (i >= D ? 2*D - 2 - i : i);
}
__device__ __forceinline__ void fma4(float4& a, float s, const float4 w) {
    a.x = fmaf(s, w.x, a.x); a.y = fmaf(s, w.y, a.y);
    a.z = fmaf(s, w.z, a.z); a.w = fmaf(s, w.w, a.w);
}

// ---------------------------------------------------------------------------
// k_pad0: build full padded volume from channels-last x_in (once, step 0).
// ---------------------------------------------------------------------------
__global__ __launch_bounds__(256)
void k_pad0(const float* __restrict__ x, float* __restrict__ xp) {
    const int idx = blockIdx.x * 256 + threadIdx.x;     // 32*NPAD exactly
    const int bc = idx / NPAD;
    int r = idx - bc * NPAD;
    const int pz = r / 2916; r -= pz * 2916;
    const int py = r / 54;
    const int px = r - py * 54;
    const int b = bc >> 4, c = bc & 15;
    const int z = refl(pz - 3), y = refl(py - 3), x0 = refl(px - 3);
    xp[(size_t)bc*PVOL + pz*PPL + py*PROW + px] =
        x[(((size_t)(b*D + z))*D + y)*D*C + x0*C + c];
}

// ---------------------------------------------------------------------------
// k_halo: refresh halo shells from interior (interior written by k_apply).
// Sources are interior, targets are halo -> disjoint, no race.
// ---------------------------------------------------------------------------
__global__ __launch_bounds__(256)
void k_halo(float* __restrict__ xp) {
    const int idx = blockIdx.x * 256 + threadIdx.x;
    const int bc = idx / NPAD;
    int r = idx - bc * NPAD;
    const int pz = r / 2916; r -= pz * 2916;
    const int py = r / 54;
    const int px = r - py * 54;
    if (pz >= 3 && pz < 51 && py >= 3 && py < 51 && px >= 3 && px < 51) return;
    const int sz = refl(pz-3) + 3, sy = refl(py-3) + 3, sx = refl(px-3) + 3;
    xp[(size_t)bc*PVOL + pz*PPL + py*PROW + px] =
        xp[(size_t)bc*PVOL + sz*PPL + sy*PROW + sx];
}

// ---------------------------------------------------------------------------
// k_wxpose: conv weights [kidx][c] -> wt[c][dy][dz][dx]. Run once.
// ---------------------------------------------------------------------------
__global__ __launch_bounds__(256)
void k_wxpose(const float* __restrict__ cw, float* __restrict__ wt) {
    int i = blockIdx.x * 256 + threadIdx.x;
    if (i < 343 * 16) {
        int kidx = i >> 4, c = i & 15;           // kidx = (dz*7+dy)*7+dx
        int dz = kidx / 49, dy = (kidx / 7) % 7, dx = kidx % 7;
        wt[((c*7 + dy)*7 + dz)*7 + dx] = cw[i];
    }
}

// ---------------------------------------------------------------------------
// k_conv v6: no LDS, no barriers; weights REGISTER-CACHED per dy (49 floats,
// compile-time indexed: dy runtime loop, pz(9) x k(3) unrolled, dz = pz-k).
// Inputs: 189 aligned float4 reads via L1/L2. Writes y1 channel-major ushort4.
// ---------------------------------------------------------------------------
__global__ __launch_bounds__(192)
void k_conv(const float* __restrict__ xp, const float* __restrict__ wt,
            const float* __restrict__ cbias, u16* __restrict__ y1m) {
    const int bid = blockIdx.x;
    const int zt = bid & 15;          // 16 z-tiles of 3
    const int yt = (bid >> 4) % 3;    // 3 y-tiles of 16
    const int c  = (bid / 48) & 15;
    const int b  = bid / 768;
    const int t  = threadIdx.x;
    const int tx = t % 12, ty = t / 12;
    const int y0 = yt * 16, z0 = zt * 3;
    const float* base = xp + (size_t)(b*16 + c) * PVOL
                           + (size_t)(y0 + ty) * PROW + 4*tx
                           + (size_t)z0 * PPL;
    const float* wc = wt + c * 343;   // [dy][dz][dx]

    float a[3][4];
    #pragma unroll
    for (int k = 0; k < 3; ++k)
        a[k][0] = a[k][1] = a[k][2] = a[k][3] = 0.f;

    for (int dy = 0; dy < 7; ++dy) {              // runtime: body fits I$
        float w[49];
        const float* wrow = wc + dy*49;
        #pragma unroll
        for (int q = 0; q < 12; ++q) {
            float4 p = *(const float4*)(wrow + q*4);
            w[q*4+0] = p.x; w[q*4+1] = p.y; w[q*4+2] = p.z; w[q*4+3] = p.w;
        }
        w[48] = wrow[48];
        const float* rowb = base + (size_t)dy * PROW;
        #pragma unroll
        for (int pz = 0; pz < 9; ++pz) {          // input plane zi = z0+pz-3
            const float* rp = rowb + (size_t)pz * PPL;
            float4 A  = *(const float4*)rp;
            float4 Bv = *(const float4*)(rp + 4);
            float4 Cv = *(const float4*)(rp + 8);
            #pragma unroll
            for (int k = 0; k < 3; ++k) {
                const int dz = pz - k;            // compile-time
                if (dz >= 0 && dz <= 6) {
                    const float w0=w[dz*7+0], w1=w[dz*7+1], w2=w[dz*7+2],
                                w3=w[dz*7+3], w4=w[dz*7+4], w5=w[dz*7+5],
                                w6=w[dz*7+6];
                    a[k][0] = fmaf(w0,A.x, fmaf(w1,A.y, fmaf(w2,A.z, fmaf(w3,A.w,
                              fmaf(w4,Bv.x, fmaf(w5,Bv.y, fmaf(w6,Bv.z, a[k][0])))))));
                    a[k][1] = fmaf(w0,A.y, fmaf(w1,A.z, fmaf(w2,A.w, fmaf(w3,Bv.x,
                              fmaf(w4,Bv.y, fmaf(w5,Bv.z, fmaf(w6,Bv.w, a[k][1])))))));
                    a[k][2] = fmaf(w0,A.z, fmaf(w1,A.w, fmaf(w2,Bv.x, fmaf(w3,Bv.y,
                              fmaf(w4,Bv.z, fmaf(w5,Bv.w, fmaf(w6,Cv.x, a[k][2])))))));
                    a[k][3] = fmaf(w0,A.w, fmaf(w1,Bv.x, fmaf(w2,Bv.y, fmaf(w3,Bv.z,
                              fmaf(w4,Bv.w, fmaf(w5,Cv.x, fmaf(w6,Cv.y, a[k][3])))))));
                }
            }
        }
    }

    const float cbv = cbias[c];
    const size_t cb_off = (size_t)(b*16 + c) * D3;
    #pragma unroll
    for (int k = 0; k < 3; ++k) {
        const size_t sp = (size_t)(z0+k)*2304 + (y0+ty)*48 + 4*tx;
        ushort4 o = { f2bf(a[k][0]+cbv), f2bf(a[k][1]+cbv),
                      f2bf(a[k][2]+cbv), f2bf(a[k][3]+cbv) };
        *(ushort4*)(y1m + cb_off + sp) = o;
    }
}

// ---------------------------------------------------------------------------
// k_fc0: h = [x|y1]@W0 + b0 -> bf16 h + deterministic BN partials.
// y1 (channel-major) staged via LDS: 4 coalesced ushort4 loads/thread ->
// ys[c][vox]; compute reads are same-address broadcasts (free).
// ---------------------------------------------------------------------------
__global__ __launch_bounds__(256)
void k_fc0(const float* __restrict__ srcx, const u16* __restrict__ y1m,
           const float* __restrict__ w0, const float* __restrict__ b0,
           u16* __restrict__ hb, float* __restrict__ partials) {
    __shared__ u16 ys[16][260];       // 8320 B
    __shared__ float red[2][8][H];    // 8192 B
    const int t = threadIdx.x;
    const int vb0 = blockIdx.x * 256;
    const int b  = vb0 / D3;
    const int sp0 = vb0 - b * D3;
    {   // stage y1 tile: 16 c x 256 vox
        const u16* yb = y1m + (size_t)b*16*D3 + sp0;
        #pragma unroll
        for (int r = 0; r < 4; ++r) {
            const int idx = t + 256*r;
            const int cc = idx >> 6, q = idx & 63;
            *(ushort4*)&ys[cc][q*4] = *(const ushort4*)(yb + (size_t)cc*D3 + q*4);
        }
    }
    const int j4 = t & 31, vg = t >> 5;
    const int j0 = j4 * 4;
    float4 wr[32];
    #pragma unroll
    for (int k = 0; k < 32; ++k) wr[k] = *(const float4*)(w0 + k*H + j0);
    const float4 bv = *(const float4*)(b0 + j0);
    __syncthreads();

    float4 sum = {0.f,0.f,0.f,0.f}, sq = {0.f,0.f,0.f,0.f};
    const int vloc = vg * 32;
    const float* xc = srcx + (size_t)(vb0 + vloc) * C;
    for (int i = 0; i < 32; ++i) {
        const int vi = vloc + i;
        float4 h = bv;
        {   // x part: 4 broadcast float4 loads
            const float4* xp4 = (const float4*)(xc + i*C);
            float4 x0 = xp4[0], x1 = xp4[1], x2 = xp4[2], x3 = xp4[3];
            fma4(h, x0.x, wr[0]);  fma4(h, x0.y, wr[1]);
            fma4(h, x0.z, wr[2]);  fma4(h, x0.w, wr[3]);
            fma4(h, x1.x, wr[4]);  fma4(h, x1.y, wr[5]);
            fma4(h, x1.z, wr[6]);  fma4(h, x1.w, wr[7]);
            fma4(h, x2.x, wr[8]);  fma4(h, x2.y, wr[9]);
            fma4(h, x2.z, wr[10]); fma4(h, x2.w, wr[11]);
            fma4(h, x3.x, wr[12]); fma4(h, x3.y, wr[13]);
            fma4(h, x3.z, wr[14]); fma4(h, x3.w, wr[15]);
        }
        #pragma unroll
        for (int k = 0; k < 16; ++k)
            fma4(h, bf2f(ys[k][vi]), wr[16+k]);
        sum.x += h.x; sum.y += h.y; sum.z += h.z; sum.w += h.w;
        sq.x = fmaf(h.x,h.x,sq.x); sq.y = fmaf(h.y,h.y,sq.y);
        sq.z = fmaf(h.z,h.z,sq.z); sq.w = fmaf(h.w,h.w,sq.w);
        ushort4 hu = { f2bf(h.x), f2bf(h.y), f2bf(h.z), f2bf(h.w) };
        *(ushort4*)(hb + (size_t)(vb0 + vi)*H + j0) = hu;
    }
    *(float4*)&red[0][vg][j0] = sum;
    *(float4*)&red[1][vg][j0] = sq;
    __syncthreads();
    const int stat = t >> 7, j = t & 127;
    float acc = 0.f;
    #pragma unroll
    for (int g = 0; g < 8; ++g) acc += red[stat][g][j];
    partials[(size_t)t * NB_FC + blockIdx.x] = acc;
}

// ---------------------------------------------------------------------------
__global__ __launch_bounds__(256)
void k_red(const float* __restrict__ partials, float* __restrict__ sums) {
    const int s = blockIdx.x, t = threadIdx.x;
    const float* row = partials + (size_t)s * NB_FC;
    float a = row[t] + row[t + 256] + row[t + 512];
    if (t + 768 < NB_FC) a += row[t + 768];
    __shared__ float l[256];
    l[t] = a; __syncthreads();
    if (t < 128) l[t] += l[t + 128];
    __syncthreads();
    if (t < 64) {
        float v = l[t] + l[t + 64];
        #pragma unroll
        for (int off = 32; off; off >>= 1) v += __shfl_down(v, off);
        if (t == 0) sums[s] = v;
    }
}

// ---------------------------------------------------------------------------
// k_apply (round-9 structure): 16 vox/block; h (bf16) streamed, BN+ReLU ->
// LDS; fc1 vs LDS-transposed W1 (staged per block); masked residual ->
// d_out (channels-last) AND padded-volume interior (halo via k_halo).
// ---------------------------------------------------------------------------
__global__ __launch_bounds__(256)
void k_apply(const u16* __restrict__ hb, const float* __restrict__ srcx,
             const float* __restrict__ w1,
             const float* __restrict__ gamma, const float* __restrict__ beta,
             const float* __restrict__ sums, const int* __restrict__ mask,
             float* __restrict__ xo, float* __restrict__ xp) {
    __shared__ float hs[16][132];
    __shared__ float w1t[16][132];   // [c][j]
    __shared__ float xs[16][17];
    const int t = threadIdx.x;
    const size_t vb = (size_t)blockIdx.x * 16;

    for (int idx = t; idx < H*C; idx += 256)
        w1t[idx & 15][idx >> 4] = w1[idx];          // w1[j][c] -> w1t[c][j]

    {   // phase A: BN-affine + ReLU into LDS
        const int j4 = t & 31, vh = t >> 5;
        const int j0 = j4 * 4;
        const float invN = 1.0f / (float)NVOX;
        const float4 sm = *(const float4*)(sums + j0);
        const float4 sQ = *(const float4*)(sums + H + j0);
        const float4 gm = *(const float4*)(gamma + j0);
        const float4 bt = *(const float4*)(beta + j0);
        float4 sc, sh;
        {
            float m0 = sm.x*invN, m1 = sm.y*invN, m2 = sm.z*invN, m3 = sm.w*invN;
            sc.x = gm.x * rsqrtf(fmaf(-m0,m0,sQ.x*invN) + BN_EPS);
            sc.y = gm.y * rsqrtf(fmaf(-m1,m1,sQ.y*invN) + BN_EPS);
            sc.z = gm.z * rsqrtf(fmaf(-m2,m2,sQ.z*invN) + BN_EPS);
            sc.w = gm.w * rsqrtf(fmaf(-m3,m3,sQ.w*invN) + BN_EPS);
            sh.x = bt.x - m0*sc.x; sh.y = bt.y - m1*sc.y;
            sh.z = bt.z - m2*sc.z; sh.w = bt.w - m3*sc.w;
        }
        #pragma unroll
        for (int rep = 0; rep < 2; ++rep) {
            const int vl = rep*8 + vh;
            ushort4 u = *(const ushort4*)(hb + (vb + vl)*H + j0);
            float4 hp;
            hp.x = fmaxf(0.f, fmaf(bf2f(u.x), sc.x, sh.x));
            hp.y = fmaxf(0.f, fmaf(bf2f(u.y), sc.y, sh.y));
            hp.z = fmaxf(0.f, fmaf(bf2f(u.z), sc.z, sh.z));
            hp.w = fmaxf(0.f, fmaf(bf2f(u.w), sc.w, sh.w));
            *(float4*)&hs[vl][j0] = hp;
        }
    }
    __syncthreads();
    {   // phase B: dx = h'@W1, masked residual, ch-0 freeze
        const int c = t & 15, vi = t >> 4;
        const size_t v = vb + vi;
        float4 acc = {0.f,0.f,0.f,0.f};
        #pragma unroll
        for (int j = 0; j < H; j += 4) {
            float4 hv = *(const float4*)&hs[vi][j];
            float4 wv = *(const float4*)&w1t[c][j];
            acc.x = fmaf(hv.x, wv.x, acc.x); acc.y = fmaf(hv.y, wv.y, acc.y);
            acc.z = fmaf(hv.z, wv.z, acc.z); acc.w = fmaf(hv.w, wv.w, acc.w);
        }
        const float dx = (acc.x + acc.y) + (acc.z + acc.w);
        const float m = (float)mask[v];
        const float xold = srcx[v*C + c];
        const float xn = (c == 0) ? xold : fmaf(dx, m, xold);
        xo[v*C + c] = xn;
        xs[c][vi] = xn;
    }
    __syncthreads();
    {   // phase C: write padded-volume interior for next step's conv
        const int c2 = t >> 4, i2 = t & 15;
        const int b = (int)(vb / D3);
        const int sp = (int)(vb % D3);
        const int z = sp / 2304, yy = (sp % 2304) / 48, x0 = sp % 48;
        xp[(size_t)(b*16 + c2)*PVOL + (size_t)(z+3)*PPL
           + (yy+3)*PROW + (x0+3) + i2] = xs[c2][i2];
    }
}

// ---------------------------------------------------------------------------
extern "C" void kernel_launch(void* const* d_in, const int* in_sizes, int n_in,
                              void* d_out, int out_size, void* d_ws, size_t ws_size,
                              hipStream_t stream) {
    const float* x_in = (const float*)d_in[0];
    const float* cw   = (const float*)d_in[1];
    const float* cb   = (const float*)d_in[2];
    const float* w0   = (const float*)d_in[3];
    const float* b0   = (const float*)d_in[4];
    const float* w1   = (const float*)d_in[5];
    const float* gm   = (const float*)d_in[6];
    const float* bt   = (const float*)d_in[7];
    const int*   mk   = (const int*)d_in[8];
    float* out = (float*)d_out;

    char* p = (char*)d_ws;
    float* xp       = (float*)p;   p += (size_t)32 * PVOL * 4;      // 20.9MB
    u16*   y1m      = (u16*)p;     p += (size_t)NVOX * C * 2;       //  7.1MB
    u16*   hb       = (u16*)p;     p += (size_t)NVOX * H * 2;       // 56.6MB
    float* partials = (float*)p;   p += (size_t)256 * NB_FC * 4;    //  0.9MB
    float* sums     = (float*)p;   p += 256 * 4;
    float* wt       = (float*)p;                                    // 343*16

    k_pad0  <<<32*NPAD/256, 256, 0, stream>>>(x_in, xp);
    k_wxpose<<<22,          256, 0, stream>>>(cw, wt);
    for (int s = 0; s < 8; ++s) {
        const float* srcx = (s == 0) ? x_in : out;
        k_conv <<<1536,    192, 0, stream>>>(xp, wt, cb, y1m);
        k_fc0  <<<NB_FC,   256, 0, stream>>>(srcx, y1m, w0, b0, hb, partials);
        k_red  <<<256,     256, 0, stream>>>(partials, sums);
        k_apply<<<NVOX/16, 256, 0, stream>>>(hb, srcx, w1, gm, bt, sums,
                                             mk + (size_t)s * NVOX, out, xp);
        if (s < 7) k_halo<<<32*NPAD/256, 256, 0, stream>>>(xp);
    }
}

// Round 12
// 1287.081 us; speedup vs baseline: 1.9369x; 1.0202x over previous
//
#include <hip/hip_runtime.h>

#define D 48
#define C 16
#define H 128
#define D3 (D*D*D)
#define NVOX (2*D3)           // 221184
#define NB_FC (NVOX/128)      // 1728 blocks for k_fc0
#define BN_EPS 1e-5f

// padded channel-major volume: [b][c][54 z][54 y][56 x]
#define PROW 56
#define PPL  (54*PROW)        // 3024
#define PVOL (54*PPL)         // 163296
#define NPAD (54*54*54)       // 157464

typedef unsigned short u16;
typedef unsigned int   u32;

__device__ __forceinline__ float bf2f(u16 u) {
    union { u32 i; float f; } p; p.i = ((u32)u) << 16; return p.f;
}
__device__ __forceinline__ u16 f2bf(float f) {
    union { float f; u32 i; } p; p.f = f;
    u32 r = p.i + 0x7fffu + ((p.i >> 16) & 1u);   // RTNE
    return (u16)(r >> 16);
}
__device__ __forceinline__ int refl(int i) {
    return i < 0 ? -i : (i >= D ? 2*D - 2 - i : i);
}
__device__ __forceinline__ void fma4(float4& a, float s, const float4 w) {
    a.x = fmaf(s, w.x, a.x); a.y = fmaf(s, w.y, a.y);
    a.z = fmaf(s, w.z, a.z); a.w = fmaf(s, w.w, a.w);
}

// ---------------------------------------------------------------------------
// k_pad0: build full padded volume from channels-last x_in (once, step 0).
// ---------------------------------------------------------------------------
__global__ __launch_bounds__(256)
void k_pad0(const float* __restrict__ x, float* __restrict__ xp) {
    const int idx = blockIdx.x * 256 + threadIdx.x;     // 32*NPAD exactly
    const int bc = idx / NPAD;
    int r = idx - bc * NPAD;
    const int pz = r / 2916; r -= pz * 2916;
    const int py = r / 54;
    const int px = r - py * 54;
    const int b = bc >> 4, c = bc & 15;
    const int z = refl(pz - 3), y = refl(py - 3), x0 = refl(px - 3);
    xp[(size_t)bc*PVOL + pz*PPL + py*PROW + px] =
        x[(((size_t)(b*D + z))*D + y)*D*C + x0*C + c];
}

// ---------------------------------------------------------------------------
// k_halo: refresh halo shells from interior (interior written by k_apply).
// ---------------------------------------------------------------------------
__global__ __launch_bounds__(256)
void k_halo(float* __restrict__ xp) {
    const int idx = blockIdx.x * 256 + threadIdx.x;
    const int bc = idx / NPAD;
    int r = idx - bc * NPAD;
    const int pz = r / 2916; r -= pz * 2916;
    const int py = r / 54;
    const int px = r - py * 54;
    if (pz >= 3 && pz < 51 && py >= 3 && py < 51 && px >= 3 && px < 51) return;
    const int sz = refl(pz-3) + 3, sy = refl(py-3) + 3, sx = refl(px-3) + 3;
    xp[(size_t)bc*PVOL + pz*PPL + py*PROW + px] =
        xp[(size_t)bc*PVOL + sz*PPL + sy*PROW + sx];
}

// ---------------------------------------------------------------------------
// k_wxpose: conv weights [kidx][c] -> wt[c][dy][dz][dx]. Run once.
// ---------------------------------------------------------------------------
__global__ __launch_bounds__(256)
void k_wxpose(const float* __restrict__ cw, float* __restrict__ wt) {
    int i = blockIdx.x * 256 + threadIdx.x;
    if (i < 343 * 16) {
        int kidx = i >> 4, c = i & 15;           // kidx = (dz*7+dy)*7+dx
        int dz = kidx / 49, dy = (kidx / 7) % 7, dx = kidx % 7;
        wt[((c*7 + dy)*7 + dz)*7 + dx] = cw[i];
    }
}

// ---------------------------------------------------------------------------
// k_conv v6 (unchanged): no LDS/barriers; weights register-cached per dy.
// ---------------------------------------------------------------------------
__global__ __launch_bounds__(192)
void k_conv(const float* __restrict__ xp, const float* __restrict__ wt,
            const float* __restrict__ cbias, u16* __restrict__ y1m) {
    const int bid = blockIdx.x;
    const int zt = bid & 15;          // 16 z-tiles of 3
    const int yt = (bid >> 4) % 3;    // 3 y-tiles of 16
    const int c  = (bid / 48) & 15;
    const int b  = bid / 768;
    const int t  = threadIdx.x;
    const int tx = t % 12, ty = t / 12;
    const int y0 = yt * 16, z0 = zt * 3;
    const float* base = xp + (size_t)(b*16 + c) * PVOL
                           + (size_t)(y0 + ty) * PROW + 4*tx
                           + (size_t)z0 * PPL;
    const float* wc = wt + c * 343;   // [dy][dz][dx]

    float a[3][4];
    #pragma unroll
    for (int k = 0; k < 3; ++k)
        a[k][0] = a[k][1] = a[k][2] = a[k][3] = 0.f;

    for (int dy = 0; dy < 7; ++dy) {              // runtime: body fits I$
        float w[49];
        const float* wrow = wc + dy*49;
        #pragma unroll
        for (int q = 0; q < 12; ++q) {
            float4 p = *(const float4*)(wrow + q*4);
            w[q*4+0] = p.x; w[q*4+1] = p.y; w[q*4+2] = p.z; w[q*4+3] = p.w;
        }
        w[48] = wrow[48];
        const float* rowb = base + (size_t)dy * PROW;
        #pragma unroll
        for (int pz = 0; pz < 9; ++pz) {          // input plane zi = z0+pz-3
            const float* rp = rowb + (size_t)pz * PPL;
            float4 A  = *(const float4*)rp;
            float4 Bv = *(const float4*)(rp + 4);
            float4 Cv = *(const float4*)(rp + 8);
            #pragma unroll
            for (int k = 0; k < 3; ++k) {
                const int dz = pz - k;            // compile-time
                if (dz >= 0 && dz <= 6) {
                    const float w0=w[dz*7+0], w1=w[dz*7+1], w2=w[dz*7+2],
                                w3=w[dz*7+3], w4=w[dz*7+4], w5=w[dz*7+5],
                                w6=w[dz*7+6];
                    a[k][0] = fmaf(w0,A.x, fmaf(w1,A.y, fmaf(w2,A.z, fmaf(w3,A.w,
                              fmaf(w4,Bv.x, fmaf(w5,Bv.y, fmaf(w6,Bv.z, a[k][0])))))));
                    a[k][1] = fmaf(w0,A.y, fmaf(w1,A.z, fmaf(w2,A.w, fmaf(w3,Bv.x,
                              fmaf(w4,Bv.y, fmaf(w5,Bv.z, fmaf(w6,Bv.w, a[k][1])))))));
                    a[k][2] = fmaf(w0,A.z, fmaf(w1,A.w, fmaf(w2,Bv.x, fmaf(w3,Bv.y,
                              fmaf(w4,Bv.z, fmaf(w5,Bv.w, fmaf(w6,Cv.x, a[k][2])))))));
                    a[k][3] = fmaf(w0,A.w, fmaf(w1,Bv.x, fmaf(w2,Bv.y, fmaf(w3,Bv.z,
                              fmaf(w4,Bv.w, fmaf(w5,Cv.x, fmaf(w6,Cv.y, a[k][3])))))));
                }
            }
        }
    }

    const float cbv = cbias[c];
    const size_t cb_off = (size_t)(b*16 + c) * D3;
    #pragma unroll
    for (int k = 0; k < 3; ++k) {
        const size_t sp = (size_t)(z0+k)*2304 + (y0+ty)*48 + 4*tx;
        ushort4 o = { f2bf(a[k][0]+cbv), f2bf(a[k][1]+cbv),
                      f2bf(a[k][2]+cbv), f2bf(a[k][3]+cbv) };
        *(ushort4*)(y1m + cb_off + sp) = o;
    }
}

// ---------------------------------------------------------------------------
// k_fc0 v12: 2 j-columns per thread -> weight cache float2 wr[32] = 64 VGPR,
// genuinely register-resident (round-11's float4 wr[32] needed 128 and was
// silently re-loaded from global every iteration: VGPR_Count=84 proved it).
// 128 voxels/block, grid 1728. y1 staged via LDS (conflict-free broadcasts).
// ---------------------------------------------------------------------------
__global__ __launch_bounds__(256)
void k_fc0(const float* __restrict__ srcx, const u16* __restrict__ y1m,
           const float* __restrict__ w0, const float* __restrict__ b0,
           u16* __restrict__ hb, float* __restrict__ partials) {
    __shared__ u16 ys[16][128];       // 4 KB: 16 c x 128 vox
    __shared__ float red[2][4][H];    // 4 KB
    const int t = threadIdx.x;
    const int vb0 = blockIdx.x * 128;
    const int b  = vb0 / D3;
    const int sp0 = vb0 - b * D3;
    {   // stage y1 tile: 512 ushort4, 2 per thread, coalesced per channel
        const u16* yb = y1m + (size_t)b*16*D3 + sp0;
        #pragma unroll
        for (int r = 0; r < 2; ++r) {
            const int idx = t + 256*r;          // 0..511
            const int cc = idx >> 5, q = idx & 31;
            *(ushort4*)&ys[cc][q*4] = *(const ushort4*)(yb + (size_t)cc*D3 + q*4);
        }
    }
    const int j2 = t & 63, vg = t >> 6;         // vg = wave index
    const int j0 = j2 * 2;
    float2 wr[32];                              // 64 VGPR weight cache
    #pragma unroll
    for (int k = 0; k < 32; ++k) wr[k] = *(const float2*)(w0 + k*H + j0);
    const float2 bv = *(const float2*)(b0 + j0);
    __syncthreads();

    float2 sum = {0.f,0.f}, sq = {0.f,0.f};
    const int vloc = vg * 32;
    const float* xc = srcx + (size_t)(vb0 + vloc) * C;
    for (int i = 0; i < 32; ++i) {
        const int vi = vloc + i;
        float h0 = bv.x, h1 = bv.y;
        {   // x part: 4 wave-uniform float4 loads
            const float4* xp4 = (const float4*)(xc + i*C);
            float4 x0 = xp4[0], x1 = xp4[1], x2 = xp4[2], x3 = xp4[3];
            h0 = fmaf(x0.x, wr[0].x,  h0); h1 = fmaf(x0.x, wr[0].y,  h1);
            h0 = fmaf(x0.y, wr[1].x,  h0); h1 = fmaf(x0.y, wr[1].y,  h1);
            h0 = fmaf(x0.z, wr[2].x,  h0); h1 = fmaf(x0.z, wr[2].y,  h1);
            h0 = fmaf(x0.w, wr[3].x,  h0); h1 = fmaf(x0.w, wr[3].y,  h1);
            h0 = fmaf(x1.x, wr[4].x,  h0); h1 = fmaf(x1.x, wr[4].y,  h1);
            h0 = fmaf(x1.y, wr[5].x,  h0); h1 = fmaf(x1.y, wr[5].y,  h1);
            h0 = fmaf(x1.z, wr[6].x,  h0); h1 = fmaf(x1.z, wr[6].y,  h1);
            h0 = fmaf(x1.w, wr[7].x,  h0); h1 = fmaf(x1.w, wr[7].y,  h1);
            h0 = fmaf(x2.x, wr[8].x,  h0); h1 = fmaf(x2.x, wr[8].y,  h1);
            h0 = fmaf(x2.y, wr[9].x,  h0); h1 = fmaf(x2.y, wr[9].y,  h1);
            h0 = fmaf(x2.z, wr[10].x, h0); h1 = fmaf(x2.z, wr[10].y, h1);
            h0 = fmaf(x2.w, wr[11].x, h0); h1 = fmaf(x2.w, wr[11].y, h1);
            h0 = fmaf(x3.x, wr[12].x, h0); h1 = fmaf(x3.x, wr[12].y, h1);
            h0 = fmaf(x3.y, wr[13].x, h0); h1 = fmaf(x3.y, wr[13].y, h1);
            h0 = fmaf(x3.z, wr[14].x, h0); h1 = fmaf(x3.z, wr[14].y, h1);
            h0 = fmaf(x3.w, wr[15].x, h0); h1 = fmaf(x3.w, wr[15].y, h1);
        }
        #pragma unroll
        for (int k = 0; k < 16; ++k) {          // y1 part: LDS broadcasts
            const float yv = bf2f(ys[k][vi]);
            h0 = fmaf(yv, wr[16+k].x, h0); h1 = fmaf(yv, wr[16+k].y, h1);
        }
        sum.x += h0; sum.y += h1;
        sq.x = fmaf(h0,h0,sq.x); sq.y = fmaf(h1,h1,sq.y);
        ushort2 hu = { f2bf(h0), f2bf(h1) };
        *(ushort2*)(hb + (size_t)(vb0 + vi)*H + j0) = hu;   // 256B/wave
    }
    *(float2*)&red[0][vg][j0] = sum;
    *(float2*)&red[1][vg][j0] = sq;
    __syncthreads();
    const int stat = t >> 7, j = t & 127;
    float acc = 0.f;
    #pragma unroll
    for (int g = 0; g < 4; ++g) acc += red[stat][g][j];
    partials[(size_t)t * NB_FC + blockIdx.x] = acc;
}

// ---------------------------------------------------------------------------
__global__ __launch_bounds__(256)
void k_red(const float* __restrict__ partials, float* __restrict__ sums) {
    const int s = blockIdx.x, t = threadIdx.x;
    const float* row = partials + (size_t)s * NB_FC;
    float a = 0.f;
    for (int i = t; i < NB_FC; i += 256) a += row[i];   // 1728 = 6.75*256
    __shared__ float l[256];
    l[t] = a; __syncthreads();
    if (t < 128) l[t] += l[t + 128];
    __syncthreads();
    if (t < 64) {
        float v = l[t] + l[t + 64];
        #pragma unroll
        for (int off = 32; off; off >>= 1) v += __shfl_down(v, off);
        if (t == 0) sums[s] = v;
    }
}

// ---------------------------------------------------------------------------
// k_apply (round-9 structure, unchanged): 16 vox/block; BN+ReLU -> LDS; fc1
// vs LDS-transposed W1; masked residual -> d_out + padded interior.
// ---------------------------------------------------------------------------
__global__ __launch_bounds__(256)
void k_apply(const u16* __restrict__ hb, const float* __restrict__ srcx,
             const float* __restrict__ w1,
             const float* __restrict__ gamma, const float* __restrict__ beta,
             const float* __restrict__ sums, const int* __restrict__ mask,
             float* __restrict__ xo, float* __restrict__ xp) {
    __shared__ float hs[16][132];
    __shared__ float w1t[16][132];   // [c][j]
    __shared__ float xs[16][17];
    const int t = threadIdx.x;
    const size_t vb = (size_t)blockIdx.x * 16;

    for (int idx = t; idx < H*C; idx += 256)
        w1t[idx & 15][idx >> 4] = w1[idx];          // w1[j][c] -> w1t[c][j]

    {   // phase A: BN-affine + ReLU into LDS
        const int j4 = t & 31, vh = t >> 5;
        const int j0 = j4 * 4;
        const float invN = 1.0f / (float)NVOX;
        const float4 sm = *(const float4*)(sums + j0);
        const float4 sQ = *(const float4*)(sums + H + j0);
        const float4 gm = *(const float4*)(gamma + j0);
        const float4 bt = *(const float4*)(beta + j0);
        float4 sc, sh;
        {
            float m0 = sm.x*invN, m1 = sm.y*invN, m2 = sm.z*invN, m3 = sm.w*invN;
            sc.x = gm.x * rsqrtf(fmaf(-m0,m0,sQ.x*invN) + BN_EPS);
            sc.y = gm.y * rsqrtf(fmaf(-m1,m1,sQ.y*invN) + BN_EPS);
            sc.z = gm.z * rsqrtf(fmaf(-m2,m2,sQ.z*invN) + BN_EPS);
            sc.w = gm.w * rsqrtf(fmaf(-m3,m3,sQ.w*invN) + BN_EPS);
            sh.x = bt.x - m0*sc.x; sh.y = bt.y - m1*sc.y;
            sh.z = bt.z - m2*sc.z; sh.w = bt.w - m3*sc.w;
        }
        #pragma unroll
        for (int rep = 0; rep < 2; ++rep) {
            const int vl = rep*8 + vh;
            ushort4 u = *(const ushort4*)(hb + (vb + vl)*H + j0);
            float4 hp;
            hp.x = fmaxf(0.f, fmaf(bf2f(u.x), sc.x, sh.x));
            hp.y = fmaxf(0.f, fmaf(bf2f(u.y), sc.y, sh.y));
            hp.z = fmaxf(0.f, fmaf(bf2f(u.z), sc.z, sh.z));
            hp.w = fmaxf(0.f, fmaf(bf2f(u.w), sc.w, sh.w));
            *(float4*)&hs[vl][j0] = hp;
        }
    }
    __syncthreads();
    {   // phase B: dx = h'@W1, masked residual, ch-0 freeze
        const int c = t & 15, vi = t >> 4;
        const size_t v = vb + vi;
        float4 acc = {0.f,0.f,0.f,0.f};
        #pragma unroll
        for (int j = 0; j < H; j += 4) {
            float4 hv = *(const float4*)&hs[vi][j];
            float4 wv = *(const float4*)&w1t[c][j];
            acc.x = fmaf(hv.x, wv.x, acc.x); acc.y = fmaf(hv.y, wv.y, acc.y);
            acc.z = fmaf(hv.z, wv.z, acc.z); acc.w = fmaf(hv.w, wv.w, acc.w);
        }
        const float dx = (acc.x + acc.y) + (acc.z + acc.w);
        const float m = (float)mask[v];
        const float xold = srcx[v*C + c];
        const float xn = (c == 0) ? xold : fmaf(dx, m, xold);
        xo[v*C + c] = xn;
        xs[c][vi] = xn;
    }
    __syncthreads();
    {   // phase C: write padded-volume interior for next step's conv
        const int c2 = t >> 4, i2 = t & 15;
        const int b = (int)(vb / D3);
        const int sp = (int)(vb % D3);
        const int z = sp / 2304, yy = (sp % 2304) / 48, x0 = sp % 48;
        xp[(size_t)(b*16 + c2)*PVOL + (size_t)(z+3)*PPL
           + (yy+3)*PROW + (x0+3) + i2] = xs[c2][i2];
    }
}

// ---------------------------------------------------------------------------
extern "C" void kernel_launch(void* const* d_in, const int* in_sizes, int n_in,
                              void* d_out, int out_size, void* d_ws, size_t ws_size,
                              hipStream_t stream) {
    const float* x_in = (const float*)d_in[0];
    const float* cw   = (const float*)d_in[1];
    const float* cb   = (const float*)d_in[2];
    const float* w0   = (const float*)d_in[3];
    const float* b0   = (const float*)d_in[4];
    const float* w1   = (const float*)d_in[5];
    const float* gm   = (const float*)d_in[6];
    const float* bt   = (const float*)d_in[7];
    const int*   mk   = (const int*)d_in[8];
    float* out = (float*)d_out;

    char* p = (char*)d_ws;
    float* xp       = (float*)p;   p += (size_t)32 * PVOL * 4;      // 20.9MB
    u16*   y1m      = (u16*)p;     p += (size_t)NVOX * C * 2;       //  7.1MB
    u16*   hb       = (u16*)p;     p += (size_t)NVOX * H * 2;       // 56.6MB
    float* partials = (float*)p;   p += (size_t)256 * NB_FC * 4;    //  1.8MB
    float* sums     = (float*)p;   p += 256 * 4;
    float* wt       = (float*)p;                                    // 343*16

    k_pad0  <<<32*NPAD/256, 256, 0, stream>>>(x_in, xp);
    k_wxpose<<<22,          256, 0, stream>>>(cw, wt);
    for (int s = 0; s < 8; ++s) {
        const float* srcx = (s == 0) ? x_in : out;
        k_conv <<<1536,    192, 0, stream>>>(xp, wt, cb, y1m);
        k_fc0  <<<NB_FC,   256, 0, stream>>>(srcx, y1m, w0, b0, hb, partials);
        k_red  <<<256,     256, 0, stream>>>(partials, sums);
        k_apply<<<NVOX/16, 256, 0, stream>>>(hb, srcx, w1, gm, bt, sums,
                                             mk + (size_t)s * NVOX, out, xp);
        if (s < 7) k_halo<<<32*NPAD/256, 256, 0, stream>>>(xp);
    }
}